// Round 14
// baseline (116.026 us; speedup 1.0000x reference)
//
#include <hip/hip_runtime.h>
#include <stdint.h>

// NFP pooling: out[b,o,i,j] = -sum_c |x[b,c,i+1,j+1] - x[b,c,i+di,j+dj]|
// x: (8,128,224,224) f32 -> out: (8,8,222,222) f32.
//
// R14: traffic cut at full parallelism. 222 = 6*37 exactly -> TROWS=6,
// SROWS=8, NT=37, 296 blocks (8 batches x 37 tiles, XCD-pinned), zero
// row-clamp waste. Staged traffic 308 -> 272 MB (1.32x input). KC=4,
// double-buffered global_load_lds w16, one syncthreads per round (R13
// proved counted-vmcnt == syncthreads here). 384 thr: 333 compute slots
// (3 rowpairs x 111 colpairs), comp unit verbatim from R10 (verified).

constexpr int C = 128;
constexpr int H = 224;
constexpr int W = 224;
constexpr int HO = 222;
constexpr int WO = 222;
constexpr int PLANE = H * W;              // 50176
constexpr int OPLANE = HO * WO;           // 49284
constexpr int KC = 4;                     // channels per stage
constexpr int ROUNDS = C / KC;            // 32
constexpr int TROWS = 6;                  // output rows per tile (222=6*37)
constexpr int SROWS = 8;                  // staged input rows (no clamping!)
constexpr int NT = 37;                    // tiles per batch
constexpr int NBLK = 8 * NT;              // 296
constexpr int NTHR = 384;                 // 6 waves
constexpr int SLOTS = KC * SROWS * (W / 4);   // 1792 16-B slots per buffer
constexpr int BUF_F = SLOTS * 4;          // 7168 floats = 28,672 B

__device__ __forceinline__ void gload16(const float* g, float* l) {
    __builtin_amdgcn_global_load_lds(
        (const __attribute__((address_space(1))) void*)g,
        (__attribute__((address_space(3))) void*)l, 16, 0, 0);
}

// one (channel, rowpair) comp: reads 4 staged rows x 4 cols at pc,
// accumulates output rows (center rows pc+W, pc+2W). Verified in R9/R10.
__device__ __forceinline__ void comp_unit(const float* pc,
                                          float (&acc0)[8][2], float (&acc1)[8][2]) {
    float v0[4], v1[4], v2[4], v3[4];
    *(float2*)&v0[0] = *(const float2*)(pc);
    *(float2*)&v0[2] = *(const float2*)(pc + 2);
    *(float2*)&v1[0] = *(const float2*)(pc + W);
    *(float2*)&v1[2] = *(const float2*)(pc + W + 2);
    *(float2*)&v2[0] = *(const float2*)(pc + 2 * W);
    *(float2*)&v2[2] = *(const float2*)(pc + 2 * W + 2);
    *(float2*)&v3[0] = *(const float2*)(pc + 3 * W);
    *(float2*)&v3[2] = *(const float2*)(pc + 3 * W + 2);

    float hh1[3], hh2[3], DR[3], DL[3], Vv[2];
#pragma unroll
    for (int k = 0; k < 3; ++k) {
        hh1[k] = __builtin_fabsf(v1[k + 1] - v1[k]);
        hh2[k] = __builtin_fabsf(v2[k + 1] - v2[k]);
        DR[k]  = __builtin_fabsf(v1[k + 1] - v2[k]);
        DL[k]  = __builtin_fabsf(v1[k] - v2[k + 1]);
    }
    Vv[0] = __builtin_fabsf(v1[1] - v2[1]);
    Vv[1] = __builtin_fabsf(v1[2] - v2[2]);

    // offset order: (0,0),(0,1),(0,2),(1,0),(1,2),(2,0),(2,1),(2,2)
#pragma unroll
    for (int q = 0; q < 2; ++q) {
        float c1 = v1[q + 1], c2 = v2[q + 1];
        acc0[0][q] += __builtin_fabsf(c1 - v0[q]);
        acc0[1][q] += __builtin_fabsf(c1 - v0[q + 1]);
        acc0[2][q] += __builtin_fabsf(c1 - v0[q + 2]);
        acc0[3][q] += hh1[q];
        acc0[4][q] += hh1[q + 1];
        acc0[5][q] += DR[q];
        acc0[6][q] += Vv[q];
        acc0[7][q] += DL[q + 1];
        acc1[0][q] += DL[q];
        acc1[1][q] += Vv[q];
        acc1[2][q] += DR[q + 1];
        acc1[3][q] += hh2[q];
        acc1[4][q] += hh2[q + 1];
        acc1[5][q] += __builtin_fabsf(c2 - v3[q]);
        acc1[6][q] += __builtin_fabsf(c2 - v3[q + 1]);
        acc1[7][q] += __builtin_fabsf(c2 - v3[q + 2]);
    }
}

__global__ __launch_bounds__(NTHR, 1)
void nfp_sad_kernel(const float* __restrict__ x, float* __restrict__ out) {
    __shared__ float lds[2][BUF_F];       // 2 x 28,672 B = 57,344 B

    int bid = blockIdx.x;
    int b = bid & 7;                      // batch == XCD (296 = 8*37)
    int t = bid >> 3;                     // row tile 0..36
    int i0 = t * TROWS;                   // staged input rows i0..i0+7 (<=223)
    int tid = threadIdx.x;

    // staging slots: v = j*384 + tid; j=0..3 full (1536), j=4: tid<256.
    // v -> c = v/448, r = (v%448)/56, k = v%56. No row clamping needed.
    const float* xb = x + (size_t)b * C * PLANE;
    int goff[5];
#pragma unroll
    for (int j = 0; j < 5; ++j) {
        int v = j * NTHR + tid;
        int vv = v < SLOTS ? v : SLOTS - 1;
        int c = vv / 448, rem = vv % 448;
        int r = rem / 56, k = rem % 56;
        goff[j] = c * PLANE + (i0 + r) * W + k * 4;
    }
    const bool tail = (tid < SLOTS - 4 * NTHR);   // 256 tail slots

#define STAGE(sidx, bufi) do {                                          \
        int off_ = (sidx) * KC * PLANE;                                 \
        float* dst_ = &lds[bufi][0];                                    \
        gload16(xb + off_ + goff[0], dst_ + (0 * NTHR + tid) * 4);      \
        gload16(xb + off_ + goff[1], dst_ + (1 * NTHR + tid) * 4);      \
        gload16(xb + off_ + goff[2], dst_ + (2 * NTHR + tid) * 4);      \
        gload16(xb + off_ + goff[3], dst_ + (3 * NTHR + tid) * 4);      \
        if (tail)                                                       \
            gload16(xb + off_ + goff[4], dst_ + (4 * NTHR + tid) * 4);  \
    } while (0)

    // compute role: tid < 333; rp = tid/111 (0..2), cp = tid%111
    bool act = tid < 333;
    int rp = act ? (tid / 111) : 0;
    int cp = act ? (tid % 111) : 0;

    float acc0[8][2], acc1[8][2];
#pragma unroll
    for (int o = 0; o < 8; ++o) {
        acc0[o][0] = acc0[o][1] = 0.0f;
        acc1[o][0] = acc1[o][1] = 0.0f;
    }

    STAGE(0, 0);
    for (int rd = 0; rd < ROUNDS; ++rd) {
        __syncthreads();                  // stage(rd) landed (drains vmcnt)
        if (rd + 1 < ROUNDS)
            STAGE(rd + 1, (rd + 1) & 1);  // refill freed buffer, 1 ahead
        if (act) {
            const float* Bf = &lds[rd & 1][0];
#pragma unroll
            for (int c = 0; c < KC; ++c)
                comp_unit(Bf + (c * SROWS + 2 * rp) * W + 2 * cp, acc0, acc1);
        }
    }

    if (act) {
        // output rows i0+2rp, i0+2rp+1 (max 6*36+5 = 221 < 222: no guards)
        int r0 = i0 + 2 * rp;
        float* ob = out + (size_t)b * 8 * OPLANE + 2 * cp;
#pragma unroll
        for (int o = 0; o < 8; ++o) {
            float* op = ob + (size_t)o * OPLANE;
            *(float2*)(op + (size_t)r0 * WO)       = make_float2(-acc0[o][0], -acc0[o][1]);
            *(float2*)(op + (size_t)(r0 + 1) * WO) = make_float2(-acc1[o][0], -acc1[o][1]);
        }
    }
}

extern "C" void kernel_launch(void* const* d_in, const int* in_sizes, int n_in,
                              void* d_out, int out_size, void* d_ws, size_t ws_size,
                              hipStream_t stream) {
    const float* x = (const float*)d_in[0];
    float* out = (float*)d_out;
    nfp_sad_kernel<<<NBLK, NTHR, 0, stream>>>(x, out);
}

// Round 17
// 52.876 us; speedup vs baseline: 2.1943x; 2.1943x over previous
//
#include <hip/hip_runtime.h>
#include <stdint.h>

// NFP pooling: out[b,o,i,j] = -sum_c |x[b,c,i+1,j+1] - x[b,c,i+di,j+dj]|
// x: (8,128,224,224) f32 -> out: (8,8,222,222) f32.
//
// R17 = R10 verbatim (best verified: 53.0 us). LDS-staged, block = 4 output
// rows x 222 cols; 32 rounds of KC=4 channels staging 6-row strips (21.5 KB)
// via global_load_lds w16, double-buffered, one syncthreads per round.
// Thread = 2col x 2row. XCD pinning: 448 blocks = 8 batches x 56 tiles,
// bid&7 = batch. 1.75 blocks/CU hides the per-round vmcnt drain (R13
// showed counted-vmcnt buys nothing here; R11/R14/R15/R16 showed taller
// tiles / balanced grids lose on residency or correctness).

constexpr int C = 128;
constexpr int H = 224;
constexpr int W = 224;
constexpr int HO = 222;
constexpr int WO = 222;
constexpr int PLANE = H * W;              // 50176
constexpr int OPLANE = HO * WO;           // 49284
constexpr int KC = 4;                     // channels per round
constexpr int ROUNDS = C / KC;            // 32
constexpr int TROWS = 4;                  // output rows per tile
constexpr int SROWS = 6;                  // staged input rows
constexpr int NT = 56;                    // row tiles per batch
constexpr int NBLK = 8 * NT;              // 448
constexpr int SLOTS = KC * SROWS * (W / 4);   // 1344 16-B slots per buffer

__device__ __forceinline__ void gload16(const float* g, float* l) {
    __builtin_amdgcn_global_load_lds(
        (const __attribute__((address_space(1))) void*)g,
        (__attribute__((address_space(3))) void*)l, 16, 0, 0);
}

__global__ __launch_bounds__(256, 1)
void nfp_sad_kernel(const float* __restrict__ x, float* __restrict__ out) {
    __shared__ float lds[2][SLOTS * 4];   // 2 x 21,504 B = 43,008 B

    int bid = blockIdx.x;
    int b = bid & 7;                      // batch == XCD (448 = 8*56)
    int t = bid >> 3;                     // row tile 0..55
    int i0 = t * TROWS;                   // first output row; staged rows i0..i0+5
    int tid = threadIdx.x;

    // staging slots: v = j*256 + tid, v < 1344.
    // v -> c = v/336, r = (v%336)/56, k = v%56 ; global row clamped to 223.
    const float* xb = x + (size_t)b * C * PLANE;
    int goff[6];
#pragma unroll
    for (int j = 0; j < 6; ++j) {
        int v = j * 256 + tid;
        int vv = v < SLOTS ? v : SLOTS - 1;
        int c = vv / 336, rem = vv % 336;
        int r = rem / 56, k = rem % 56;
        int row = i0 + r; if (row > H - 1) row = H - 1;
        goff[j] = c * PLANE + row * W + k * 4;
    }

    // compute role: tid < 222; rp = tid/111 (0..1), cp = tid%111
    bool act = tid < 222;
    int rp = act ? (tid / 111) : 0;
    int cp = act ? (tid % 111) : 0;

    float acc0[8][2], acc1[8][2];
#pragma unroll
    for (int o = 0; o < 8; ++o) {
        acc0[o][0] = acc0[o][1] = 0.0f;
        acc1[o][0] = acc1[o][1] = 0.0f;
    }

    // stage round 0
    {
        float* dst = &lds[0][0];
#pragma unroll
        for (int j = 0; j < 5; ++j)
            gload16(xb + goff[j], dst + (j * 256 + tid) * 4);
        if (tid < 64)                     // wave-uniform tail (wave 0)
            gload16(xb + goff[5], dst + (5 * 256 + tid) * 4);
    }

    int choff = 0;                        // channel offset (floats)
    for (int rd = 0; rd < ROUNDS; ++rd) {
        __syncthreads();                  // stage(rd) complete (drains vmcnt)

        if (rd + 1 < ROUNDS) {            // issue DMA for next round
            int noff = choff + KC * PLANE;
            float* dst = &lds[(rd + 1) & 1][0];
#pragma unroll
            for (int j = 0; j < 5; ++j)
                gload16(xb + noff + goff[j], dst + (j * 256 + tid) * 4);
            if (tid < 64)
                gload16(xb + noff + goff[5], dst + (5 * 256 + tid) * 4);
        }

        if (act) {
            const float* Bf = &lds[rd & 1][0];
#pragma unroll
            for (int c = 0; c < KC; ++c) {
                // staged rows 2rp..2rp+3, cols 2cp..2cp+3
                const float* pc = Bf + (c * SROWS + 2 * rp) * W + 2 * cp;
                float v0[4], v1[4], v2[4], v3[4];
                *(float2*)&v0[0] = *(const float2*)(pc);
                *(float2*)&v0[2] = *(const float2*)(pc + 2);
                *(float2*)&v1[0] = *(const float2*)(pc + W);
                *(float2*)&v1[2] = *(const float2*)(pc + W + 2);
                *(float2*)&v2[0] = *(const float2*)(pc + 2 * W);
                *(float2*)&v2[2] = *(const float2*)(pc + 2 * W + 2);
                *(float2*)&v3[0] = *(const float2*)(pc + 3 * W);
                *(float2*)&v3[2] = *(const float2*)(pc + 3 * W + 2);

                float hh1[3], hh2[3], DR[3], DL[3], Vv[2];
#pragma unroll
                for (int k = 0; k < 3; ++k) {
                    hh1[k] = __builtin_fabsf(v1[k + 1] - v1[k]);
                    hh2[k] = __builtin_fabsf(v2[k + 1] - v2[k]);
                    DR[k]  = __builtin_fabsf(v1[k + 1] - v2[k]);
                    DL[k]  = __builtin_fabsf(v1[k] - v2[k + 1]);
                }
                Vv[0] = __builtin_fabsf(v1[1] - v2[1]);
                Vv[1] = __builtin_fabsf(v1[2] - v2[2]);

                // offset order: (0,0),(0,1),(0,2),(1,0),(1,2),(2,0),(2,1),(2,2)
#pragma unroll
                for (int q = 0; q < 2; ++q) {
                    float c1 = v1[q + 1], c2 = v2[q + 1];
                    acc0[0][q] += __builtin_fabsf(c1 - v0[q]);
                    acc0[1][q] += __builtin_fabsf(c1 - v0[q + 1]);
                    acc0[2][q] += __builtin_fabsf(c1 - v0[q + 2]);
                    acc0[3][q] += hh1[q];
                    acc0[4][q] += hh1[q + 1];
                    acc0[5][q] += DR[q];
                    acc0[6][q] += Vv[q];
                    acc0[7][q] += DL[q + 1];
                    acc1[0][q] += DL[q];
                    acc1[1][q] += Vv[q];
                    acc1[2][q] += DR[q + 1];
                    acc1[3][q] += hh2[q];
                    acc1[4][q] += hh2[q + 1];
                    acc1[5][q] += __builtin_fabsf(c2 - v3[q]);
                    acc1[6][q] += __builtin_fabsf(c2 - v3[q + 1]);
                    acc1[7][q] += __builtin_fabsf(c2 - v3[q + 2]);
                }
            }
        }
        choff += KC * PLANE;
    }

    if (act) {
        int r0 = i0 + 2 * rp;             // first of this thread's 2 output rows
        float* ob = out + (size_t)b * 8 * OPLANE + 2 * cp;
#pragma unroll
        for (int o = 0; o < 8; ++o) {
            float* op = ob + (size_t)o * OPLANE;
            if (r0 < HO)
                *(float2*)(op + (size_t)r0 * WO) = make_float2(-acc0[o][0], -acc0[o][1]);
            if (r0 + 1 < HO)
                *(float2*)(op + (size_t)(r0 + 1) * WO) = make_float2(-acc1[o][0], -acc1[o][1]);
        }
    }
}

extern "C" void kernel_launch(void* const* d_in, const int* in_sizes, int n_in,
                              void* d_out, int out_size, void* d_ws, size_t ws_size,
                              hipStream_t stream) {
    const float* x = (const float*)d_in[0];
    float* out = (float*)d_out;
    nfp_sad_kernel<<<NBLK, 256, 0, stream>>>(x, out);
}